// Round 1
// baseline (324.682 us; speedup 1.0000x reference)
//
#include <hip/hip_runtime.h>
#include <hip/hip_bf16.h>
#include <math.h>

#define BB   8
#define CINC 64
#define COUTC 64
#define HH   96
#define WW   96
#define HW   (HH*WW)           // 9216
#define BN_EPS 1e-5f

// ---- workspace layout (bytes) ----
#define OFF_W4   0
#define SZ_W4    (BB*9*HW*16)          // 10,616,832  float4 per (b,k,pixel)
#define OFF_XT   (OFF_W4 + SZ_W4)
#define SZ_XT    (BB*HW*CINC*2)        // 9,437,184   bf16 x transposed (B,H,W,C)
#define OFF_XY   (OFF_XT + SZ_XT)
#define SZ_XY    (BB*9*HW*4)           // 2,654,208   packed clamped tap indices
#define OFF_WT   (OFF_XY + SZ_XY)
#define SZ_WT    (576*64*4)            // 147,456     wT[ck][o]
#define OFF_WALL (OFF_WT + SZ_WT)
#define SZ_WALL  (576*27*4)            // 62,208      fused offset+mod conv weights

// ---------------- prep: weight transposes ----------------
__global__ __launch_bounds__(256) void prep_kernel(
    const float* __restrict__ weight, const float* __restrict__ offw,
    const float* __restrict__ modw,
    float* __restrict__ wT, float* __restrict__ wAll) {
  int tid = blockIdx.x * 256 + threadIdx.x;
  if (tid < 576 * 64) {
    int ck = tid >> 6, o = tid & 63;
    int k = ck >> 6, c = ck & 63;               // ck = k*64 + c
    wT[tid] = weight[o * 576 + c * 9 + k];
  }
  int t2 = tid - 576 * 64;
  if (t2 >= 0 && t2 < 576 * 27) {
    int ck2 = t2 / 27, oc = t2 % 27;            // ck2 = c*9 + kk
    wAll[t2] = (oc < 18) ? offw[oc * 576 + ck2] : modw[(oc - 18) * 576 + ck2];
  }
}

// ---------------- transpose x -> (B,H,W,C) bf16 ----------------
__global__ __launch_bounds__(256) void transpose_x_kernel(
    const float* __restrict__ x, __hip_bfloat16* __restrict__ xT) {
  int tid = blockIdx.x * 256 + threadIdx.x;     // over B*HW*64, c fastest
  int c = tid & 63;
  int r = tid >> 6;                             // b*HW + hw
  int b = r / HW;
  int hw = r - b * HW;
  xT[tid] = __float2bfloat16(x[(b * CINC + c) * HW + hw]);
}

// ---------------- offset/mod convs + fold into sample weights ----------------
__global__ __launch_bounds__(256) void conv_coords_kernel(
    const float* __restrict__ x, const float* __restrict__ wAll,
    const float* __restrict__ offb, const float* __restrict__ modb,
    float4* __restrict__ w4, unsigned* __restrict__ xy) {
  int pix = blockIdx.x * 256 + threadIdx.x;     // 73728 pixels
  int b = pix / HW;
  int hw = pix - b * HW;
  int h = hw / WW;
  int w = hw - h * WW;

  float acc[27];
#pragma unroll
  for (int i = 0; i < 27; i++) acc[i] = 0.f;

  bool vy[3], vx[3];
#pragma unroll
  for (int i = 0; i < 3; i++) {
    int y = h + i - 1;  vy[i] = (y >= 0) && (y < HH);
    int xx = w + i - 1; vx[i] = (xx >= 0) && (xx < WW);
  }

  const float* xb = x + b * CINC * HW;
  for (int c = 0; c < CINC; c++) {
    const float* xp = xb + c * HW;
    float xv[9];
#pragma unroll
    for (int ky = 0; ky < 3; ky++)
#pragma unroll
      for (int kx = 0; kx < 3; kx++) {
        int y = h + ky - 1, xx = w + kx - 1;
        xv[ky * 3 + kx] = (vy[ky] && vx[kx]) ? xp[y * WW + xx] : 0.f;
      }
    const float* wp = wAll + c * 9 * 27;        // uniform address -> scalar loads
#pragma unroll
    for (int kk = 0; kk < 9; kk++) {
      float xvv = xv[kk];
#pragma unroll
      for (int oc = 0; oc < 27; oc++)
        acc[oc] += xvv * wp[kk * 27 + oc];
    }
  }

#pragma unroll
  for (int k = 0; k < 9; k++) {
    int ky = k / 3, kx = k % 3;
    float offy = acc[2 * k] + offb[2 * k];
    float offx = acc[2 * k + 1] + offb[2 * k + 1];
    float mz = acc[18 + k] + modb[k];
    float mod = 2.f / (1.f + __expf(-mz));      // 2*sigmoid

    float py = (float)(h - 1 + ky) + offy;
    float px = (float)(w - 1 + kx) + offx;
    float y0f = floorf(py), x0f = floorf(px);
    float dy = py - y0f, dx = px - x0f;
    int y0 = (int)y0f, x0 = (int)x0f;
    int y1 = y0 + 1, x1 = x0 + 1;
    bool vy0 = (y0 >= 0) && (y0 < HH), vy1 = (y1 >= 0) && (y1 < HH);
    bool vx0 = (x0 >= 0) && (x0 < WW), vx1 = (x1 >= 0) && (x1 < WW);
    float w00 = (vy0 && vx0) ? (1.f - dy) * (1.f - dx) * mod : 0.f;
    float w01 = (vy0 && vx1) ? (1.f - dy) * dx * mod : 0.f;
    float w10 = (vy1 && vx0) ? dy * (1.f - dx) * mod : 0.f;
    float w11 = (vy1 && vx1) ? dy * dx * mod : 0.f;
    int y0c = min(max(y0, 0), HH - 1), y1c = min(max(y1, 0), HH - 1);
    int x0c = min(max(x0, 0), WW - 1), x1c = min(max(x1, 0), WW - 1);
    unsigned pk = (unsigned)y0c | ((unsigned)y1c << 8) |
                  ((unsigned)x0c << 16) | ((unsigned)x1c << 24);
    int idx = (b * 9 + k) * HW + hw;
    w4[idx] = make_float4(w00, w01, w10, w11);
    xy[idx] = pk;
  }
}

// ---------------- fused deformable sample + 64x576 matvec + BN + ReLU ----------------
__global__ __launch_bounds__(256) void dcn_main_kernel(
    const __hip_bfloat16* __restrict__ xT,
    const float4* __restrict__ w4, const unsigned* __restrict__ xy,
    const float* __restrict__ wT,
    const float* __restrict__ bias, const float* __restrict__ gamma,
    const float* __restrict__ beta, const float* __restrict__ mean,
    const float* __restrict__ var,
    float* __restrict__ out) {
  __shared__ float s_lds[16 * 576];
  __shared__ float o_lds[64 * 17];

  int tid = threadIdx.x;
  int wv = tid >> 6, lane = tid & 63;
  int base = blockIdx.x * 16;                   // 16 pixels per block, same row
  int b = base / HW;
  int hwb = base - b * HW;
  int h = hwb / WW;
  int wbase = hwb - h * WW;

  // ---- phase A: sampling, lane = channel ----
  const __hip_bfloat16* xb = xT + b * HW * 64;
#pragma unroll
  for (int p = 0; p < 4; p++) {
    int pl = wv * 4 + p;
    int hw = h * WW + wbase + pl;
#pragma unroll
    for (int k = 0; k < 9; k++) {
      int idx = (b * 9 + k) * HW + hw;
      float4 wj = w4[idx];
      unsigned pk = xy[idx];
      int y0 = pk & 255, y1 = (pk >> 8) & 255, x0 = (pk >> 16) & 255, x1 = pk >> 24;
      float v00 = __bfloat162float(xb[(y0 * WW + x0) * 64 + lane]);
      float v01 = __bfloat162float(xb[(y0 * WW + x1) * 64 + lane]);
      float v10 = __bfloat162float(xb[(y1 * WW + x0) * 64 + lane]);
      float v11 = __bfloat162float(xb[(y1 * WW + x1) * 64 + lane]);
      s_lds[pl * 576 + k * 64 + lane] = wj.x * v00 + wj.y * v01 + wj.z * v10 + wj.w * v11;
    }
  }
  // no barrier: each wave consumes only rows it wrote

  // ---- phase B: matvec, lane = out channel ----
  float acc0 = 0.f, acc1 = 0.f, acc2 = 0.f, acc3 = 0.f;
  const float* srow = &s_lds[(wv * 4) * 576];
  for (int ck = 0; ck < 576; ck += 4) {
    float wa = wT[(ck + 0) * 64 + lane];
    float wb = wT[(ck + 1) * 64 + lane];
    float wc = wT[(ck + 2) * 64 + lane];
    float wd = wT[(ck + 3) * 64 + lane];
    float4 s0 = *(const float4*)&srow[0 * 576 + ck];
    float4 s1 = *(const float4*)&srow[1 * 576 + ck];
    float4 s2 = *(const float4*)&srow[2 * 576 + ck];
    float4 s3 = *(const float4*)&srow[3 * 576 + ck];
    acc0 += s0.x * wa + s0.y * wb + s0.z * wc + s0.w * wd;
    acc1 += s1.x * wa + s1.y * wb + s1.z * wc + s1.w * wd;
    acc2 += s2.x * wa + s2.y * wb + s2.z * wc + s2.w * wd;
    acc3 += s3.x * wa + s3.y * wb + s3.z * wc + s3.w * wd;
  }

  // ---- epilogue: bias + BN + ReLU ----
  float bs = bias[lane], mn = mean[lane];
  float inv = gamma[lane] * rsqrtf(var[lane] + BN_EPS);
  float bt = beta[lane];
  float r0 = fmaxf((acc0 + bs - mn) * inv + bt, 0.f);
  float r1 = fmaxf((acc1 + bs - mn) * inv + bt, 0.f);
  float r2 = fmaxf((acc2 + bs - mn) * inv + bt, 0.f);
  float r3 = fmaxf((acc3 + bs - mn) * inv + bt, 0.f);
  o_lds[lane * 17 + wv * 4 + 0] = r0;
  o_lds[lane * 17 + wv * 4 + 1] = r1;
  o_lds[lane * 17 + wv * 4 + 2] = r2;
  o_lds[lane * 17 + wv * 4 + 3] = r3;
  __syncthreads();

  // ---- coalesced store ----
  int wq = tid & 15, og = tid >> 4;             // og in [0,16)
#pragma unroll
  for (int it = 0; it < 4; it++) {
    int o = og + it * 16;
    out[(b * COUTC + o) * HW + h * WW + wbase + wq] = o_lds[o * 17 + wq];
  }
}

extern "C" void kernel_launch(void* const* d_in, const int* in_sizes, int n_in,
                              void* d_out, int out_size, void* d_ws, size_t ws_size,
                              hipStream_t stream) {
  const float* x      = (const float*)d_in[0];
  const float* offw   = (const float*)d_in[1];
  const float* offb   = (const float*)d_in[2];
  const float* modw   = (const float*)d_in[3];
  const float* modb   = (const float*)d_in[4];
  const float* weight = (const float*)d_in[5];
  const float* bias   = (const float*)d_in[6];
  const float* gamma  = (const float*)d_in[7];
  const float* beta   = (const float*)d_in[8];
  const float* mean   = (const float*)d_in[9];
  const float* var    = (const float*)d_in[10];

  char* ws = (char*)d_ws;
  float4*         w4   = (float4*)(ws + OFF_W4);
  __hip_bfloat16* xT   = (__hip_bfloat16*)(ws + OFF_XT);
  unsigned*       xybuf= (unsigned*)(ws + OFF_XY);
  float*          wT   = (float*)(ws + OFF_WT);
  float*          wAll = (float*)(ws + OFF_WALL);

  prep_kernel<<<205, 256, 0, stream>>>(weight, offw, modw, wT, wAll);
  transpose_x_kernel<<<18432, 256, 0, stream>>>(x, xT);
  conv_coords_kernel<<<288, 256, 0, stream>>>(x, wAll, offb, modb, w4, xybuf);
  dcn_main_kernel<<<4608, 256, 0, stream>>>(xT, w4, xybuf, wT, bias, gamma, beta,
                                            mean, var, (float*)d_out);
}

// Round 2
// 148.989 us; speedup vs baseline: 2.1792x; 2.1792x over previous
//
#include <hip/hip_runtime.h>
#include <hip/hip_bf16.h>
#include <math.h>

#define BB 8
#define HH 96
#define WW 96
#define HW 9216
#define BN_EPS 1e-5f

typedef short bf16x8 __attribute__((ext_vector_type(8)));
typedef float f32x4 __attribute__((ext_vector_type(4)));

// ---- workspace layout (bytes) ----
#define OFF_W4   0
#define SZ_W4    (BB*9*HW*16)          // float4 per (b,k,pixel)
#define OFF_XT   (OFF_W4 + SZ_W4)
#define SZ_XT    (BB*HW*64*2)          // bf16 x transposed (B,H,W,C)
#define OFF_XY   (OFF_XT + SZ_XT)
#define SZ_XY    (BB*9*HW*4)           // packed clamped tap indices
#define OFF_WB   (OFF_XY + SZ_XY)
#define SZ_WB    (64*576*2)            // wB[o][ck] bf16, ck = k*64+c
#define OFF_WALL (OFF_WB + SZ_WB)
#define SZ_WALL  (576*27*4)            // wAll[c*9+kk][27] f32

// ---------------- prep: weight transposes ----------------
__global__ __launch_bounds__(256) void prep_kernel(
    const float* __restrict__ weight, const float* __restrict__ offw,
    const float* __restrict__ modw,
    __hip_bfloat16* __restrict__ wB, float* __restrict__ wAll) {
  int tid = blockIdx.x * 256 + threadIdx.x;
  if (tid < 64 * 576) {
    int o = tid / 576, ck = tid % 576;
    int k = ck >> 6, c = ck & 63;                // ck = k*64 + c
    wB[tid] = __float2bfloat16(weight[o * 576 + c * 9 + k]);
  }
  int t2 = tid - 64 * 576;
  if (t2 >= 0 && t2 < 576 * 27) {
    int ck2 = t2 / 27, oc = t2 % 27;             // ck2 = c*9 + kk
    wAll[t2] = (oc < 18) ? offw[oc * 576 + ck2] : modw[(oc - 18) * 576 + ck2];
  }
}

// ---------------- LDS-tiled transpose x -> (B,H,W,C) bf16 ----------------
__global__ __launch_bounds__(256) void transpose_x_kernel(
    const float* __restrict__ x, __hip_bfloat16* __restrict__ xT) {
  __shared__ float tile[64][65];
  int tid = threadIdx.x;
  int b = blockIdx.x / 144, hwb = (blockIdx.x % 144) * 64;
  int col = tid & 63, g = tid >> 6;
#pragma unroll
  for (int it = 0; it < 16; ++it) {
    int c = it * 4 + g;
    tile[c][col] = x[(b * 64 + c) * HW + hwb + col];   // coalesced 256B
  }
  __syncthreads();
#pragma unroll
  for (int it = 0; it < 16; ++it) {
    int p = it * 4 + g;
    xT[(size_t)(b * HW + hwb + p) * 64 + col] = __float2bfloat16(tile[col][p]);
  }
}

// ---------------- offset/mod convs (channel-split x4) + fold ----------------
__global__ __launch_bounds__(256) void conv_coords_kernel(
    const float* __restrict__ x, const float* __restrict__ wAll,
    const float* __restrict__ offb, const float* __restrict__ modb,
    float4* __restrict__ w4, unsigned* __restrict__ xy) {
  __shared__ float s_r[4][64][29];
  int tid = threadIdx.x;
  int pxl = tid & 63;
  int cg = __builtin_amdgcn_readfirstlane(tid >> 6);   // wave-uniform -> s_loads
  int pix = blockIdx.x * 64 + pxl;
  int b = pix / HW, hw = pix - b * HW;
  int h = hw / WW, w = hw - h * WW;

  bool vy[3], vx[3];
#pragma unroll
  for (int i = 0; i < 3; i++) {
    int y = h + i - 1;  vy[i] = (y >= 0) && (y < HH);
    int xx = w + i - 1; vx[i] = (xx >= 0) && (xx < WW);
  }

  float acc[27];
#pragma unroll
  for (int i = 0; i < 27; i++) acc[i] = 0.f;

  const float* xb = x + b * 64 * HW;
  for (int ci = 0; ci < 16; ++ci) {
    int c = cg * 16 + ci;
    const float* xp = xb + c * HW;
    float xv[9];
#pragma unroll
    for (int ky = 0; ky < 3; ky++)
#pragma unroll
      for (int kx = 0; kx < 3; kx++) {
        int y = h + ky - 1, xx = w + kx - 1;
        xv[ky * 3 + kx] = (vy[ky] && vx[kx]) ? xp[y * WW + xx] : 0.f;
      }
    const float* wp = wAll + c * 243;                  // uniform -> SMEM
#pragma unroll
    for (int kk = 0; kk < 9; kk++) {
      float xvv = xv[kk];
#pragma unroll
      for (int oc = 0; oc < 27; oc++)
        acc[oc] += xvv * wp[kk * 27 + oc];
    }
  }
#pragma unroll
  for (int i = 0; i < 27; i++) s_r[cg][pxl][i] = acc[i];
  __syncthreads();

  for (int it = tid; it < 576; it += 256) {
    int px = it & 63, k = it >> 6;
    int pix2 = blockIdx.x * 64 + px;
    int b2 = pix2 / HW, hw2 = pix2 - b2 * HW;
    int h2 = hw2 / WW, w2 = hw2 - h2 * WW;
    int ky = k / 3, kx = k - ky * 3;

    float a0 = s_r[0][px][2 * k] + s_r[1][px][2 * k] + s_r[2][px][2 * k] + s_r[3][px][2 * k];
    float a1 = s_r[0][px][2 * k + 1] + s_r[1][px][2 * k + 1] + s_r[2][px][2 * k + 1] + s_r[3][px][2 * k + 1];
    float a2 = s_r[0][px][18 + k] + s_r[1][px][18 + k] + s_r[2][px][18 + k] + s_r[3][px][18 + k];

    float offy = a0 + offb[2 * k];
    float offx = a1 + offb[2 * k + 1];
    float mod = 2.f / (1.f + __expf(-(a2 + modb[k])));

    float py = (float)(h2 - 1 + ky) + offy;
    float px_ = (float)(w2 - 1 + kx) + offx;
    float y0f = floorf(py), x0f = floorf(px_);
    float dy = py - y0f, dx = px_ - x0f;
    int y0 = (int)y0f, x0 = (int)x0f;
    int y1 = y0 + 1, x1 = x0 + 1;
    bool vy0 = (y0 >= 0) && (y0 < HH), vy1 = (y1 >= 0) && (y1 < HH);
    bool vx0 = (x0 >= 0) && (x0 < WW), vx1 = (x1 >= 0) && (x1 < WW);
    float w00 = (vy0 && vx0) ? (1.f - dy) * (1.f - dx) * mod : 0.f;
    float w01 = (vy0 && vx1) ? (1.f - dy) * dx * mod : 0.f;
    float w10 = (vy1 && vx0) ? dy * (1.f - dx) * mod : 0.f;
    float w11 = (vy1 && vx1) ? dy * dx * mod : 0.f;
    int y0c = min(max(y0, 0), HH - 1), y1c = min(max(y1, 0), HH - 1);
    int x0c = min(max(x0, 0), WW - 1), x1c = min(max(x1, 0), WW - 1);
    unsigned pk = (unsigned)y0c | ((unsigned)y1c << 8) |
                  ((unsigned)x0c << 16) | ((unsigned)x1c << 24);
    int idx = (b2 * 9 + k) * HW + hw2;
    w4[idx] = make_float4(w00, w01, w10, w11);
    xy[idx] = pk;
  }
}

// ---------------- fused deformable sample + MFMA GEMM + BN + ReLU ----------------
__global__ __launch_bounds__(256) void dcn_main_kernel(
    const __hip_bfloat16* __restrict__ xT,
    const float4* __restrict__ w4, const unsigned* __restrict__ xy,
    const __hip_bfloat16* __restrict__ wB,
    const float* __restrict__ bias, const float* __restrict__ gamma,
    const float* __restrict__ beta, const float* __restrict__ mean,
    const float* __restrict__ var,
    float* __restrict__ out) {
  __shared__ __attribute__((aligned(16))) __hip_bfloat16 s_A[32 * 584];
  float* o_lds = (float*)s_A;                          // aliased after barrier

  int tid = threadIdx.x;
  int lane = tid & 63;
  int wv = __builtin_amdgcn_readfirstlane(tid >> 6);

  int bi = blockIdx.x;
  int b = bi / 288, r0 = bi % 288;
  int h = r0 / 3, w0 = (r0 - (r0 / 3) * 3) * 32;
  int hwrow = h * WW + w0;

  // ---- phase A: deformable sampling, lane = channel, 8 pixels/wave ----
  const __hip_bfloat16* xb = xT + (size_t)b * HW * 64;
#pragma unroll 2
  for (int p8 = 0; p8 < 8; ++p8) {
    int pl = wv * 8 + p8;
    int hw = hwrow + pl;
#pragma unroll
    for (int k = 0; k < 9; ++k) {
      int idx = (b * 9 + k) * HW + hw;                 // wave-uniform -> s_load
      float4 wj = w4[idx];
      unsigned pk = xy[idx];
      int y0 = pk & 255, y1 = (pk >> 8) & 255, x0 = (pk >> 16) & 255, x1 = pk >> 24;
      float v00 = __bfloat162float(xb[(y0 * WW + x0) * 64 + lane]);
      float v01 = __bfloat162float(xb[(y0 * WW + x1) * 64 + lane]);
      float v10 = __bfloat162float(xb[(y1 * WW + x0) * 64 + lane]);
      float v11 = __bfloat162float(xb[(y1 * WW + x1) * 64 + lane]);
      float s = wj.x * v00 + wj.y * v01 + wj.z * v10 + wj.w * v11;
      s_A[pl * 584 + k * 64 + lane] = __float2bfloat16(s);
    }
  }
  __syncthreads();

  // ---- phase B: [32 x 576] x [576 x 64] bf16 MFMA ----
  int r = lane & 15, g = lane >> 4;
  int mt = wv >> 1, ntp = wv & 1;
  const __hip_bfloat16* arow = s_A + (mt * 16 + r) * 584 + g * 8;
  const __hip_bfloat16* b0p = wB + (ntp * 32 + r) * 576 + g * 8;
  const __hip_bfloat16* b1p = b0p + 16 * 576;
  f32x4 acc0 = {0.f, 0.f, 0.f, 0.f}, acc1 = {0.f, 0.f, 0.f, 0.f};
#pragma unroll 3
  for (int s = 0; s < 18; ++s) {
    bf16x8 a   = *(const bf16x8*)(arow + s * 32);
    bf16x8 bb0 = *(const bf16x8*)(b0p + s * 32);
    bf16x8 bb1 = *(const bf16x8*)(b1p + s * 32);
    acc0 = __builtin_amdgcn_mfma_f32_16x16x32_bf16(a, bb0, acc0, 0, 0, 0);
    acc1 = __builtin_amdgcn_mfma_f32_16x16x32_bf16(a, bb1, acc1, 0, 0, 0);
  }

  // ---- epilogue: bias + BN + ReLU, LDS transpose, coalesced store ----
  int o0 = ntp * 32 + r, o1 = o0 + 16;
  float bs0 = bias[o0] - mean[o0], bs1 = bias[o1] - mean[o1];
  float inv0 = gamma[o0] * rsqrtf(var[o0] + BN_EPS);
  float inv1 = gamma[o1] * rsqrtf(var[o1] + BN_EPS);
  float bt0 = beta[o0], bt1 = beta[o1];
  __syncthreads();                                     // all s_A reads done
#pragma unroll
  for (int j = 0; j < 4; ++j) {
    int px = mt * 16 + g * 4 + j;                      // C row = (lane>>4)*4+j
    o_lds[o0 * 36 + px] = fmaxf((acc0[j] + bs0) * inv0 + bt0, 0.f);
    o_lds[o1 * 36 + px] = fmaxf((acc1[j] + bs1) * inv1 + bt1, 0.f);
  }
  __syncthreads();

  int oo = tid >> 2, q = tid & 3;
  float4 u0 = *(const float4*)&o_lds[oo * 36 + q * 8];
  float4 u1 = *(const float4*)&o_lds[oo * 36 + q * 8 + 4];
  float* op = out + (size_t)(b * 64 + oo) * HW + hwrow + q * 8;
  *(float4*)op = u0;
  *(float4*)(op + 4) = u1;
}

extern "C" void kernel_launch(void* const* d_in, const int* in_sizes, int n_in,
                              void* d_out, int out_size, void* d_ws, size_t ws_size,
                              hipStream_t stream) {
  const float* x      = (const float*)d_in[0];
  const float* offw   = (const float*)d_in[1];
  const float* offb   = (const float*)d_in[2];
  const float* modw   = (const float*)d_in[3];
  const float* modb   = (const float*)d_in[4];
  const float* weight = (const float*)d_in[5];
  const float* bias   = (const float*)d_in[6];
  const float* gamma  = (const float*)d_in[7];
  const float* beta   = (const float*)d_in[8];
  const float* mean   = (const float*)d_in[9];
  const float* var    = (const float*)d_in[10];

  char* ws = (char*)d_ws;
  float4*         w4    = (float4*)(ws + OFF_W4);
  __hip_bfloat16* xT    = (__hip_bfloat16*)(ws + OFF_XT);
  unsigned*       xybuf = (unsigned*)(ws + OFF_XY);
  __hip_bfloat16* wB    = (__hip_bfloat16*)(ws + OFF_WB);
  float*          wAll  = (float*)(ws + OFF_WALL);

  prep_kernel<<<205, 256, 0, stream>>>(weight, offw, modw, wB, wAll);
  transpose_x_kernel<<<1152, 256, 0, stream>>>(x, xT);
  conv_coords_kernel<<<1152, 256, 0, stream>>>(x, wAll, offb, modb, w4, xybuf);
  dcn_main_kernel<<<2304, 256, 0, stream>>>(xT, w4, xybuf, wB, bias, gamma, beta,
                                            mean, var, (float*)d_out);
}